// Round 1
// 146.223 us; speedup vs baseline: 1.0790x; 1.0790x over previous
//
#include <hip/hip_runtime.h>
#include <hip/hip_bf16.h>
#include <math.h>

// Problem constants (from reference)
#define D_BINS 59
#define CTX    80
#define O_TOT  139      // D_BINS + CTX
#define K_CIN  256
#define PIXELS 704      // 16*44
#define BNPAIR 24       // B*N = 4*6
#define BEVHW  16384    // 128*128
#define NBATCH 4

// Coarse binning: tile = 8 rows x 16 cols of BEV cells -> 128 cells/tile,
// 128 tiles/batch, 512 buckets. ~1947 points/bucket, ~15 points/cell.
#define NTILE   128
#define NBUCKET (NBATCH * NTILE)            // 512
#define TCELLS  128

// Fused fill: one plist region per y==0 GEMM block (64 px x 59 bins).
#define NBLK    264                         // 24 bn * 11 ptiles
#define SEGS    66                          // segments/bucket = 6 cams * 11 ptiles
#define EPB     (64 * D_BINS)               // 3,776 entries per block region

// Gather LDS list capacity (bucket mean 1947, sd ~44; slow-path covers >CAP).
#define CAP     2816
#define CAPP    (CAP + TCELLS * 7)          // + max pad-to-8 slack

// Workspace layout (4B units): ctx bf16 first, then count/offset mats, plist.
#define CTX_OFF    0
#define CTX_F      (BNPAIR * PIXELS * CTX / 2)   // 675,840 floats of bf16
#define CNTMAT_OFF (CTX_OFF + CTX_F)
#define OFSMAT_OFF (CNTMAT_OFF + NBLK * NTILE)
#define PLIST_OFF  (OFSMAT_OFF + NBLK * NTILE)   // even -> uint2 aligned

// ---------------------------------------------------------------------------
// Kernel 1: per-(b,n) GEMM, 64x64 tile, 4x4 micro-tile, K-step 16 (math
// identical to prior version). y==0 blocks additionally fuse softmax over the
// 59 depth rows + binning (the former fill_kernel): logits never hit HBM.
// ---------------------------------------------------------------------------
__global__ __launch_bounds__(256) void gemm_fused(
    const float* __restrict__ img,    // (BNPAIR, 256, 704)
    const float* __restrict__ w,      // (139, 256)
    const float* __restrict__ bias,   // (139)
    const int*   __restrict__ geom,   // (bn, 59, 704, 2)
    __hip_bfloat16* __restrict__ ctx, // (bn, 704, 80) context, BF16
    uint2*       __restrict__ plist,  // [NBLK][EPB]
    int*         __restrict__ cntmat, // [NBLK][NTILE]
    int*         __restrict__ ofsmat) // [NBLK][NTILE]
{
    __shared__ float As[16][64];    // [k][o_local]
    __shared__ float Bs[16][64];    // [k][p_local]
    __shared__ float red[16][64];   // softmax partials [ty][px_local]
    __shared__ int lh[NTILE], lofs[NTILE], lcur[NTILE], sscan[NTILE];

    const int tid = threadIdx.x;
    const int tx  = tid & 15;
    const int ty  = tid >> 4;
    const int bn  = blockIdx.z;
    const int by  = blockIdx.y;
    const int o0  = by * 64;
    const int p0  = blockIdx.x * 64;

    const float* imgbn = img + (size_t)bn * K_CIN * PIXELS;

    float acc[4][4];
#pragma unroll
    for (int i = 0; i < 4; ++i)
#pragma unroll
        for (int j = 0; j < 4; ++j) acc[i][j] = 0.f;

    const int a_ol = tid >> 2;          // 0..63
    const int a_kc = (tid & 3) * 4;     // 0,4,8,12
    const int b_kl = tid >> 4;          // 0..15
    const int b_p4 = (tid & 15) * 4;    // 0..60

    for (int kt = 0; kt < K_CIN; kt += 16) {
        {
            const int o = o0 + a_ol;
            float4 v = make_float4(0.f, 0.f, 0.f, 0.f);
            if (o < O_TOT) v = *(const float4*)&w[(size_t)o * K_CIN + kt + a_kc];
            As[a_kc + 0][a_ol] = v.x;
            As[a_kc + 1][a_ol] = v.y;
            As[a_kc + 2][a_ol] = v.z;
            As[a_kc + 3][a_ol] = v.w;
        }
        *(float4*)&Bs[b_kl][b_p4] =
            *(const float4*)&imgbn[(size_t)(kt + b_kl) * PIXELS + p0 + b_p4];
        __syncthreads();

#pragma unroll
        for (int kk = 0; kk < 16; ++kk) {
            const float4 a = *(const float4*)&As[kk][ty * 4];
            const float4 b = *(const float4*)&Bs[kk][tx * 4];
            const float av[4] = {a.x, a.y, a.z, a.w};
            const float bv[4] = {b.x, b.y, b.z, b.w};
#pragma unroll
            for (int i = 0; i < 4; ++i)
#pragma unroll
                for (int j = 0; j < 4; ++j)
                    acc[i][j] += av[i] * bv[j];
        }
        __syncthreads();
    }

    if (by == 0) {
        // ---- bias into registers (all 64 rows valid here) ----
        float bvv[4];
#pragma unroll
        for (int i = 0; i < 4; ++i) bvv[i] = bias[ty * 4 + i];
#pragma unroll
        for (int i = 0; i < 4; ++i)
#pragma unroll
            for (int j = 0; j < 4; ++j) acc[i][j] += bvv[i];

        // ---- softmax over o=0..58, cross-ty via LDS (rows 0..14 hold data) ----
        float pm[4] = {-INFINITY, -INFINITY, -INFINITY, -INFINITY};
#pragma unroll
        for (int i = 0; i < 4; ++i) {
            if (ty * 4 + i < D_BINS) {
#pragma unroll
                for (int j = 0; j < 4; ++j) pm[j] = fmaxf(pm[j], acc[i][j]);
            }
        }
#pragma unroll
        for (int j = 0; j < 4; ++j) red[ty][tx * 4 + j] = pm[j];
        __syncthreads();
        float gm[4] = {-INFINITY, -INFINITY, -INFINITY, -INFINITY};
        for (int t = 0; t < 15; ++t) {
            const float4 r = *(const float4*)&red[t][tx * 4];
            gm[0] = fmaxf(gm[0], r.x); gm[1] = fmaxf(gm[1], r.y);
            gm[2] = fmaxf(gm[2], r.z); gm[3] = fmaxf(gm[3], r.w);
        }
        __syncthreads();                 // gm reads done before red reuse
        float ps[4] = {0.f, 0.f, 0.f, 0.f};
#pragma unroll
        for (int i = 0; i < 4; ++i) {
            if (ty * 4 + i < D_BINS) {
#pragma unroll
                for (int j = 0; j < 4; ++j) {
                    const float e = __expf(acc[i][j] - gm[j]);
                    acc[i][j] = e;
                    ps[j] += e;
                }
            }
        }
#pragma unroll
        for (int j = 0; j < 4; ++j) red[ty][tx * 4 + j] = (ty < 15) ? ps[j] : 0.f;
        if (tid < NTILE) lh[tid] = 0;    // hist init rides the same barrier
        __syncthreads();
        float gs[4] = {0.f, 0.f, 0.f, 0.f};
        for (int t = 0; t < 15; ++t) {
            const float4 r = *(const float4*)&red[t][tx * 4];
            gs[0] += r.x; gs[1] += r.y; gs[2] += r.z; gs[3] += r.w;
        }
        float inv[4];
#pragma unroll
        for (int j = 0; j < 4; ++j) inv[j] = 1.f / gs[j];

        // ---- binning: geom -> (tile,cell), LDS histogram ----
        const int2* g2 = (const int2*)geom;
        unsigned bc[4][4];
#pragma unroll
        for (int i = 0; i < 4; ++i) {
            const int o = ty * 4 + i;
            if (o < D_BINS) {
                const size_t gidx = ((size_t)(bn * D_BINS + o)) * PIXELS + p0 + tx * 4;
                const int4 ga = *(const int4*)&g2[gidx];       // (x0,y0,x1,y1)
                const int4 gb = *(const int4*)&g2[gidx + 2];   // (x2,y2,x3,y3)
                const int gx[4] = {ga.x, ga.z, gb.x, gb.z};
                const int gy[4] = {ga.y, ga.w, gb.y, gb.w};
#pragma unroll
                for (int j = 0; j < 4; ++j) {
                    const int tile = (gx[j] >> 3) * 8 + (gy[j] >> 4);
                    const int cell = (gx[j] & 7) * 16 + (gy[j] & 15);
                    bc[i][j] = (unsigned)((tile << 7) | cell);
                    atomicAdd(&lh[tile], 1);
                }
            }
        }
        __syncthreads();

        // ---- 128-wide inclusive scan of tile counts ----
        if (tid < NTILE) sscan[tid] = lh[tid];
        __syncthreads();
#pragma unroll
        for (int off = 1; off < NTILE; off <<= 1) {
            const int t = (tid < NTILE && tid >= off) ? sscan[tid - off] : 0;
            __syncthreads();
            if (tid < NTILE) sscan[tid] += t;
            __syncthreads();
        }
        const int blk = bn * 11 + blockIdx.x;
        if (tid < NTILE) {
            const int excl = sscan[tid] - lh[tid];
            lofs[tid] = excl;
            lcur[tid] = 0;
            cntmat[(size_t)blk * NTILE + tid] = lh[tid];
            ofsmat[(size_t)blk * NTILE + tid] = excl;
        }
        __syncthreads();

        // ---- scatter entries into this block's plist region ----
        uint2* dst = plist + (size_t)blk * EPB;
#pragma unroll
        for (int j = 0; j < 4; ++j) {
            const unsigned ctxoff = (unsigned)((bn * PIXELS + p0 + tx * 4 + j) * CTX);
#pragma unroll
            for (int i = 0; i < 4; ++i) {
                const int o = ty * 4 + i;
                if (o < D_BINS) {
                    const unsigned u = bc[i][j];
                    const int t = (int)(u >> 7);
                    const int pos = lofs[t] + atomicAdd(&lcur[t], 1);
                    dst[pos] = make_uint2(__float_as_uint(acc[i][j] * inv[j]),
                                          (ctxoff << 7) | (u & 127u));
                }
            }
        }

        // ---- ctx rows o=59..63 (bias already added) ----
#pragma unroll
        for (int i = 0; i < 4; ++i) {
            const int o = ty * 4 + i;
            if (o >= D_BINS) {
                const int c = o - D_BINS;
                __hip_bfloat16* cdst = ctx + ((size_t)bn * PIXELS + p0 + tx * 4) * CTX + c;
#pragma unroll
                for (int j = 0; j < 4; ++j)
                    cdst[(size_t)j * CTX] = __float2bfloat16(acc[i][j]);
            }
        }
    } else {
        // ctx-only epilogue (o >= 64 > D_BINS always)
#pragma unroll
        for (int i = 0; i < 4; ++i) {
            const int o = o0 + ty * 4 + i;
            if (o >= O_TOT) continue;
            const float bvv = bias[o];
            const int c = o - D_BINS;
            __hip_bfloat16* cdst = ctx + ((size_t)bn * PIXELS + p0 + tx * 4) * CTX + c;
#pragma unroll
            for (int j = 0; j < 4; ++j)
                cdst[(size_t)j * CTX] = __float2bfloat16(acc[i][j] + bvv);
        }
    }
}

// ---------------------------------------------------------------------------
// Kernel 2 (gather): one block per bucket. 66 segments (~29.5 pts each) ->
// bufA -> cell-sort into bufB (pad-to-8). Accumulate: lane l<40 owns channel
// pair (2l,2l+1), ONE u32 (=2xbf16) load per point, unpacked by shift.
// ---------------------------------------------------------------------------
__global__ __launch_bounds__(1024) void gather_kernel(
    const uint2* __restrict__ plist,
    const int*   __restrict__ cntmat,
    const int*   __restrict__ ofsmat,
    const unsigned short* __restrict__ ctx,   // bf16 bits, (bn,pix,80)
    float*       __restrict__ out)
{
    __shared__ float sacc[CTX][TCELLS + 1];   // 41.3 KB
    __shared__ uint2 bufB[CAPP];              // 29 KB
    __shared__ int sg[128];
    __shared__ int segcnt[SEGS], segofs[SEGS];
    __shared__ int cellcnt[TCELLS], celloff[TCELLS], cellcur[TCELLS], sc[TCELLS];
    uint2* bufA = (uint2*)sacc;               // overlay: bufA dead once sacc live

    const int tid    = threadIdx.x;
    const int wv     = tid >> 6;
    const int lane   = tid & 63;
    const int bucket = blockIdx.x;
    const int b      = bucket >> 7;
    const int tile   = bucket & 127;
    const int blk0   = b * SEGS;

    // scan of the 66 segment counts (padded to 128)
    if (tid < 128) {
        const int c = (tid < SEGS) ? cntmat[(size_t)(blk0 + tid) * NTILE + tile] : 0;
        sg[tid] = c;
        if (tid < SEGS) segcnt[tid] = c;
    }
    __syncthreads();
#pragma unroll
    for (int off = 1; off < 128; off <<= 1) {
        const int t = (tid < 128 && tid >= off) ? sg[tid - off] : 0;
        __syncthreads();
        if (tid < 128) sg[tid] += t;
        __syncthreads();
    }
    if (tid < SEGS) segofs[tid] = sg[tid] - segcnt[tid];
    __syncthreads();
    const int total = sg[127];

    for (int sgi = wv; sgi < SEGS; sgi += 16) {
        const int n = segcnt[sgi];
        if (!n) continue;
        const int dstb = segofs[sgi];
        const uint2* sp = plist + (size_t)(blk0 + sgi) * EPB
                          + ofsmat[(size_t)(blk0 + sgi) * NTILE + tile];
        for (int i = lane; i < n; i += 64) {
            const int d = dstb + i;
            if (d < CAP) bufA[d] = sp[i];
        }
    }
    const int ncap = (total < CAP) ? total : CAP;
    __syncthreads();

    // cell histogram
    if (tid < TCELLS) cellcnt[tid] = 0;
    __syncthreads();
    for (int i = tid; i < ncap; i += 1024)
        atomicAdd(&cellcnt[bufA[i].y & 127u], 1);
    __syncthreads();
    // scan over PADDED counts (round up to 8)
    if (tid < TCELLS) sc[tid] = (cellcnt[tid] + 7) & ~7;
    __syncthreads();
#pragma unroll
    for (int off = 1; off < TCELLS; off <<= 1) {
        const int t = (tid < TCELLS && tid >= off) ? sc[tid - off] : 0;
        __syncthreads();
        if (tid < TCELLS) sc[tid] += t;
        __syncthreads();
    }
    if (tid < TCELLS) {
        celloff[tid] = sc[tid] - ((cellcnt[tid] + 7) & ~7);
        cellcur[tid] = 0;
    }
    __syncthreads();
    const int padtotal = sc[TCELLS - 1];
    // zero pad region (pads: depth=0 -> contribute 0; ctxoff=0 harmless)
    for (int i = tid; i < padtotal; i += 1024) bufB[i] = make_uint2(0u, 0u);
    __syncthreads();
    // reorder bufA -> bufB (cell-sorted, padded)
    for (int i = tid; i < ncap; i += 1024) {
        const uint2 e = bufA[i];
        const int c = (int)(e.y & 127u);
        bufB[celloff[c] + atomicAdd(&cellcur[c], 1)] = e;
    }
    __syncthreads();   // bufA dead; sacc live from here

    // accumulate: wave wv owns cells c = wv, wv+16, ...; lane l<40 owns
    // channels (2l, 2l+1); 8-pt unrolled, one u32 (2xbf16) load per point.
    for (int c = wv; c < TCELLS; c += 16) {
        const int s0 = celloff[c];
        const int pc = (cellcnt[c] + 7) & ~7;
        float a0 = 0.f, a1 = 0.f;
        for (int i = 0; i < pc; i += 8) {
            uint2 e[8];
#pragma unroll
            for (int r = 0; r < 8; ++r) e[r] = bufB[s0 + i + r];   // broadcast
            if (lane < 40) {
                unsigned u[8];
#pragma unroll
                for (int r = 0; r < 8; ++r)
                    u[r] = *(const unsigned*)(ctx + (e[r].y >> 7) + 2 * lane);
#pragma unroll
                for (int r = 0; r < 8; ++r) {
                    const float d  = __uint_as_float(e[r].x);
                    const float f0 = __uint_as_float(u[r] << 16);
                    const float f1 = __uint_as_float(u[r] & 0xffff0000u);
                    a0 += d * f0;
                    a1 += d * f1;
                }
            }
        }
        if (lane < 40) {
            sacc[2 * lane][c]     = a0;
            sacc[2 * lane + 1][c] = a1;
        }
    }

    // slow path for bucket overflow (~20 sigma; correctness only)
    if (total > CAP) {
        for (int sgi = 0; sgi < SEGS; ++sgi) {
            const int dstb = segofs[sgi];
            const int n    = segcnt[sgi];
            if (dstb + n <= CAP) continue;
            const uint2* sp = plist + (size_t)(blk0 + sgi) * EPB
                              + ofsmat[(size_t)(blk0 + sgi) * NTILE + tile];
            const int i0 = (CAP > dstb) ? (CAP - dstb) : 0;
            for (int i = i0; i < n; ++i) {
                const uint2 e = sp[i];
                const int c = (int)(e.y & 127u);
                if ((c & 15) == wv && lane < 40) {
                    const unsigned u = *(const unsigned*)(ctx + (e.y >> 7) + 2 * lane);
                    const float dep = __uint_as_float(e.x);
                    sacc[2 * lane][c]     += dep * __uint_as_float(u << 16);
                    sacc[2 * lane + 1][c] += dep * __uint_as_float(u & 0xffff0000u);
                }
            }
        }
    }
    __syncthreads();

    // epilogue: full 64B line writes to (B,C,H,W)
    const int tl = bucket & 127;
    const int tr = tl >> 3;
    const int tc = tl & 7;
    const int c0  = tid >> 4;
    const int col = tid & 15;
#pragma unroll
    for (int cc = c0; cc < CTX; cc += 64) {
#pragma unroll
        for (int r = 0; r < 8; ++r) {
            out[((size_t)(b * CTX + cc)) * BEVHW + (tr * 8 + r) * 128 + tc * 16 + col]
                = sacc[cc][r * 16 + col];
        }
    }
}

extern "C" void kernel_launch(void* const* d_in, const int* in_sizes, int n_in,
                              void* d_out, int out_size, void* d_ws, size_t ws_size,
                              hipStream_t stream)
{
    const float* img  = (const float*)d_in[0];
    const float* w    = (const float*)d_in[4];
    const float* bias = (const float*)d_in[5];
    const int*   geom = (const int*)d_in[6];
    float*       out  = (float*)d_out;

    float* ws     = (float*)d_ws;
    __hip_bfloat16* ctx = (__hip_bfloat16*)(ws + CTX_OFF);
    int*   cntmat = (int*)(ws + CNTMAT_OFF);
    int*   ofsmat = (int*)(ws + OFSMAT_OFF);
    uint2* plist  = (uint2*)(ws + PLIST_OFF);

    // 1. GEMM + bias; y==0 blocks fuse softmax + deterministic binning
    {
        dim3 grid(11, 3, BNPAIR);   // 64-pixel tiles (704 = 11*64 exact)
        gemm_fused<<<grid, 256, 0, stream>>>(img, w, bias, geom, ctx,
                                             plist, cntmat, ofsmat);
    }
    // 2. fused cell-sort + gather per bucket, coalesced (B,C,H,W) writes
    gather_kernel<<<NBUCKET, 1024, 0, stream>>>(plist, cntmat, ofsmat,
                                                (const unsigned short*)ctx, out);
}

// Round 2
// 144.467 us; speedup vs baseline: 1.0921x; 1.0122x over previous
//
#include <hip/hip_runtime.h>
#include <hip/hip_bf16.h>
#include <math.h>

// Problem constants
#define D_BINS 59
#define CTX    80
#define O_TOT  139
#define O_PAD  144      // padded to 9 MFMA row-tiles
#define K_CIN  256
#define PIXELS 704
#define BNPAIR 24
#define BEVHW  16384
#define NBATCH 4

// BEV binning: tile = 8 rows x 16 cols -> 128 cells, 128 tiles/batch.
#define NTILE   128
#define NBUCKET (NBATCH * NTILE)   // 512
#define TCELLS  128

// gemm blocks: 32 px each -> 528 blocks (2.06/CU, balanced), 128 threads.
#define PXT    32
#define NPXT   22                  // 704/32
#define NBLK   (BNPAIR * NPXT)     // 528
#define SEGS   (6 * NPXT)          // 132 segments per bucket
#define EPB    (PXT * D_BINS)      // 1888 entries per block region

#define CAP    2816
#define CAPP   (CAP + TCELLS * 7)

// Workspace layout (4B units)
#define WHL_F      36864                         // 2 planes * 144*256 bf16
#define CTX_OFF    (WHL_F)
#define CTX_F      (BNPAIR * PIXELS * CTX / 2)   // bf16 ctx
#define CNTMAT_OFF (CTX_OFF + CTX_F)
#define OFSMAT_OFF (CNTMAT_OFF + NBLK * NTILE)
#define PLIST_OFF  (OFSMAT_OFF + NBLK * NTILE)

typedef __attribute__((ext_vector_type(8))) short bf16x8;
typedef __attribute__((ext_vector_type(4))) float f32x4;

__device__ __forceinline__ unsigned short f2bf(float v) {
    __hip_bfloat16 h = __float2bfloat16(v);   // RNE
    return *reinterpret_cast<unsigned short*>(&h);
}
__device__ __forceinline__ float bf2f(unsigned short u) {
    return __uint_as_float(((unsigned)u) << 16);
}

// ---------------------------------------------------------------------------
// Kernel 0: split W (139x256 fp32) into bf16 hi/lo planes [144][256] (pad=0).
// ---------------------------------------------------------------------------
__global__ __launch_bounds__(256) void wsplit_kernel(
    const float* __restrict__ w, unsigned short* __restrict__ whl)
{
    const int row = blockIdx.x;        // 0..143
    const int col = threadIdx.x;       // 0..255
    const float v = (row < O_TOT) ? w[(size_t)row * K_CIN + col] : 0.f;
    const unsigned short hi = f2bf(v);
    const unsigned short lo = f2bf(v - bf2f(hi));
    whl[row * K_CIN + col]            = hi;
    whl[36864 + row * K_CIN + col]    = lo;
}

// ---------------------------------------------------------------------------
// Kernel 1: MFMA GEMM (bf16 hi/lo split, 3 products ~= fp32) + fused softmax
// + binning epilogue. Block = full O (144 rows) x 32 px, 128 threads (2 waves,
// each wave owns a 16-px subtile, 9 o-tiles). Frag layout per m89/m92/m97:
// A: lane = A[l&15][8*(l>>4)+e]; B (transposed in LDS [px][k]) same pattern;
// D: row=(l>>4)*4+reg, col=l&15. Granule-XOR swizzle -> 2-way (free) on reads.
// ---------------------------------------------------------------------------
__global__ __launch_bounds__(128) void gemm_fused(
    const float* __restrict__ img,            // (24, 256, 704)
    const unsigned short* __restrict__ whl,   // 2 planes [144][256] bf16 bits
    const float* __restrict__ bias,           // (139)
    const int*   __restrict__ geom,           // (24, 59, 704, 2)
    __hip_bfloat16* __restrict__ ctx,         // (24, 704, 80) bf16
    uint2*       __restrict__ plist,          // [NBLK][EPB]
    int*         __restrict__ cntmat,         // [NBLK][NTILE]
    int*         __restrict__ ofsmat)         // [NBLK][NTILE]
{
    __shared__ __align__(16) unsigned char sW[2][O_PAD * 64];   // 9216 B each
    __shared__ __align__(16) unsigned char sI[2][PXT * 64];     // 2048 B each
    __shared__ float sbias[O_PAD];
    __shared__ int lh[NTILE], lofs[NTILE], lcur[NTILE], sscan[NTILE];

    const int tid  = threadIdx.x;
    const int lane = tid & 63;
    const int wv   = tid >> 6;                 // 0..1
    const int bn   = blockIdx.y;
    const int p0   = blockIdx.x * PXT;

    sbias[tid] = bias[tid];                    // tid<128 < 139
    if (tid < 16) sbias[128 + tid] = (128 + tid < O_TOT) ? bias[128 + tid] : 0.f;
    lh[tid] = 0;

    const float* imgbn = img + (size_t)bn * K_CIN * PIXELS;

    f32x4 acc[9];
#pragma unroll
    for (int t = 0; t < 9; ++t) acc[t] = (f32x4){0.f, 0.f, 0.f, 0.f};

    const int k2  = tid >> 3;                  // 0..15 -> k-rows 2k2, 2k2+1
    const int px4 = (tid & 7) * 4;             // 0..28

    for (int ks = 0; ks < 8; ++ks) {
        const int k0 = ks * 32;
        __syncthreads();                       // prior compute done
        // ---- stage W hi/lo k-slice [144][32] with granule swizzle ----
#pragma unroll
        for (int pl = 0; pl < 2; ++pl) {
            for (int c = tid; c < 576; c += 128) {
                const int row = c >> 2, g = c & 3;
                const int gs  = g ^ ((row >> 1) & 3);
                *(float4*)&sW[pl][row * 64 + gs * 16] =
                    *(const float4*)&whl[pl * 36864 + row * K_CIN + k0 + g * 8];
            }
        }
        // ---- stage I k-slice: fp32 -> bf16 hi/lo, transposed [px][k] ----
        {
            const float4 v0 = *(const float4*)&imgbn[(size_t)(k0 + 2 * k2) * PIXELS + p0 + px4];
            const float4 v1 = *(const float4*)&imgbn[(size_t)(k0 + 2 * k2 + 1) * PIXELS + p0 + px4];
            const float a0[4] = {v0.x, v0.y, v0.z, v0.w};
            const float a1[4] = {v1.x, v1.y, v1.z, v1.w};
#pragma unroll
            for (int j = 0; j < 4; ++j) {
                const int px  = px4 + j;
                const int gs  = (k2 >> 2) ^ ((px >> 1) & 3);
                const int off = px * 64 + gs * 16 + 4 * (k2 & 3);
                const unsigned short h0 = f2bf(a0[j]);
                const unsigned short h1 = f2bf(a1[j]);
                const unsigned short l0 = f2bf(a0[j] - bf2f(h0));
                const unsigned short l1 = f2bf(a1[j] - bf2f(h1));
                *(unsigned*)&sI[0][off] = (unsigned)h0 | ((unsigned)h1 << 16);
                *(unsigned*)&sI[1][off] = (unsigned)l0 | ((unsigned)l1 << 16);
            }
        }
        __syncthreads();
        // ---- MFMA: wave wv -> px-subtile wv*16; 9 o-tiles x 3 products ----
        const int m = lane & 15;
        const int g = lane >> 4;
        const int bpx = wv * 16 + m;
        const int bgs = g ^ ((bpx >> 1) & 3);
        const bf16x8 bhi = *(const bf16x8*)&sI[0][bpx * 64 + bgs * 16];
        const bf16x8 blo = *(const bf16x8*)&sI[1][bpx * 64 + bgs * 16];
#pragma unroll
        for (int t = 0; t < 9; ++t) {
            const int row = t * 16 + m;
            const int ags = g ^ ((row >> 1) & 3);
            const bf16x8 ahi = *(const bf16x8*)&sW[0][row * 64 + ags * 16];
            const bf16x8 alo = *(const bf16x8*)&sW[1][row * 64 + ags * 16];
            acc[t] = __builtin_amdgcn_mfma_f32_16x16x32_bf16(ahi, bhi, acc[t], 0, 0, 0);
            acc[t] = __builtin_amdgcn_mfma_f32_16x16x32_bf16(ahi, blo, acc[t], 0, 0, 0);
            acc[t] = __builtin_amdgcn_mfma_f32_16x16x32_bf16(alo, bhi, acc[t], 0, 0, 0);
        }
    }

    // ---- epilogue: lane holds C[o=16t+4q+r][pxg], q=lane>>4 ----
    const int m   = lane & 15;
    const int q   = lane >> 4;
    const int px_local = wv * 16 + m;
    const int pxg = p0 + px_local;

    // bias
#pragma unroll
    for (int t = 0; t < 9; ++t)
#pragma unroll
        for (int r = 0; r < 4; ++r) acc[t][r] += sbias[t * 16 + q * 4 + r];

    // softmax over o<59: local (t<=3 masked) then shfl over the 4 q-lanes
    float gm = -INFINITY;
#pragma unroll
    for (int t = 0; t < 4; ++t)
#pragma unroll
        for (int r = 0; r < 4; ++r)
            if (16 * t + 4 * q + r < D_BINS) gm = fmaxf(gm, acc[t][r]);
    gm = fmaxf(gm, __shfl_xor(gm, 16));
    gm = fmaxf(gm, __shfl_xor(gm, 32));
    float ls = 0.f;
#pragma unroll
    for (int t = 0; t < 4; ++t)
#pragma unroll
        for (int r = 0; r < 4; ++r)
            if (16 * t + 4 * q + r < D_BINS) {
                const float e = __expf(acc[t][r] - gm);
                acc[t][r] = e;
                ls += e;
            }
    ls += __shfl_xor(ls, 16);
    ls += __shfl_xor(ls, 32);
    const float inv = 1.f / ls;

    __syncthreads();   // K-loop LDS reads done -> sctx overlay safe; lh ready

    // ---- binning: geom -> (tile,cell), histogram; ctx rows -> LDS stage ----
    unsigned short* sctx = (unsigned short*)&sW[0][0];   // [PXT][80] bf16
    const int2* g2 = (const int2*)geom;
    unsigned bc[4][4];
#pragma unroll
    for (int t = 0; t < 4; ++t)
#pragma unroll
        for (int r = 0; r < 4; ++r) {
            const int o = 16 * t + 4 * q + r;
            if (o < D_BINS) {
                const int2 gg = g2[((size_t)(bn * D_BINS + o)) * PIXELS + pxg];
                const int tile = (gg.x >> 3) * 8 + (gg.y >> 4);
                const int cell = (gg.x & 7) * 16 + (gg.y & 15);
                bc[t][r] = (unsigned)((tile << 7) | cell);
                atomicAdd(&lh[tile], 1);
            }
        }
#pragma unroll
    for (int t = 3; t < 9; ++t)
#pragma unroll
        for (int r = 0; r < 4; ++r) {
            const int c = 16 * t + 4 * q + r - D_BINS;
            if (c >= 0 && c < CTX) sctx[px_local * CTX + c] = f2bf(acc[t][r]);
        }
    __syncthreads();

    // ---- 128-wide scan of tile counts (128 threads exactly) ----
    sscan[tid] = lh[tid];
    __syncthreads();
#pragma unroll
    for (int off = 1; off < NTILE; off <<= 1) {
        const int t = (tid >= off) ? sscan[tid - off] : 0;
        __syncthreads();
        sscan[tid] += t;
        __syncthreads();
    }
    const int blk = bn * NPXT + blockIdx.x;
    {
        const int excl = sscan[tid] - lh[tid];
        lofs[tid] = excl;
        lcur[tid] = 0;
        cntmat[(size_t)blk * NTILE + tid] = lh[tid];
        ofsmat[(size_t)blk * NTILE + tid] = excl;
    }
    __syncthreads();

    // ---- scatter plist + ctx writeout (coalesced b128) ----
    uint2* dst = plist + (size_t)blk * EPB;
    const unsigned ctxoff = (unsigned)((bn * PIXELS + pxg) * CTX);
#pragma unroll
    for (int t = 0; t < 4; ++t)
#pragma unroll
        for (int r = 0; r < 4; ++r) {
            const int o = 16 * t + 4 * q + r;
            if (o < D_BINS) {
                const unsigned u = bc[t][r];
                const int tl = (int)(u >> 7);
                const int pos = lofs[tl] + atomicAdd(&lcur[tl], 1);
                dst[pos] = make_uint2(__float_as_uint(acc[t][r] * inv),
                                      (ctxoff << 7) | (u & 127u));
            }
        }
    {
        const char* sb = (const char*)sctx;
        char* gb = (char*)ctx + ((size_t)(bn * PIXELS) + p0) * CTX * 2;
        for (int i = tid; i < PXT * CTX * 2 / 16; i += 128)   // 320 chunks
            *(float4*)(gb + i * 16) = *(const float4*)(sb + i * 16);
    }
}

// ---------------------------------------------------------------------------
// Kernel 2 (gather): one block per bucket. 132 segments (~15 pts each),
// copied by 16-lane subgroups -> bufA -> cell-sort into bufB (pad-to-8).
// Lane l<40 owns channel pair (2l,2l+1), one u32 (2xbf16) load per point.
// ---------------------------------------------------------------------------
__global__ __launch_bounds__(1024) void gather_kernel(
    const uint2* __restrict__ plist,
    const int*   __restrict__ cntmat,
    const int*   __restrict__ ofsmat,
    const unsigned short* __restrict__ ctx,
    float*       __restrict__ out)
{
    __shared__ float sacc[CTX][TCELLS + 1];   // 41.3 KB
    __shared__ uint2 bufB[CAPP];              // 29 KB
    __shared__ int sg[256];
    __shared__ int segcnt[SEGS], segofs[SEGS];
    __shared__ int cellcnt[TCELLS], celloff[TCELLS], cellcur[TCELLS], sc[TCELLS];
    uint2* bufA = (uint2*)sacc;

    const int tid    = threadIdx.x;
    const int wv     = tid >> 6;
    const int lane   = tid & 63;
    const int bucket = blockIdx.x;
    const int b      = bucket >> 7;
    const int tile   = bucket & 127;
    const int blk0   = b * SEGS;

    // scan of 132 segment counts (padded to 256)
    if (tid < 256) {
        const int c = (tid < SEGS) ? cntmat[(size_t)(blk0 + tid) * NTILE + tile] : 0;
        sg[tid] = c;
        if (tid < SEGS) segcnt[tid] = c;
    }
    __syncthreads();
#pragma unroll
    for (int off = 1; off < 256; off <<= 1) {
        const int t = (tid < 256 && tid >= off) ? sg[tid - off] : 0;
        __syncthreads();
        if (tid < 256) sg[tid] += t;
        __syncthreads();
    }
    if (tid < SEGS) segofs[tid] = sg[tid] - segcnt[tid];
    __syncthreads();
    const int total = sg[255];

    // segment copy: 16-lane subgroups (64 subgroups over 132 segs)
    {
        const int sub = lane >> 4;
        const int sl  = lane & 15;
        for (int sgi = wv * 4 + sub; sgi < SEGS; sgi += 64) {
            const int n = segcnt[sgi];
            if (!n) continue;
            const int dstb = segofs[sgi];
            const uint2* sp = plist + (size_t)(blk0 + sgi) * EPB
                              + ofsmat[(size_t)(blk0 + sgi) * NTILE + tile];
            for (int i = sl; i < n; i += 16) {
                const int d = dstb + i;
                if (d < CAP) bufA[d] = sp[i];
            }
        }
    }
    const int ncap = (total < CAP) ? total : CAP;
    __syncthreads();

    // cell histogram
    if (tid < TCELLS) cellcnt[tid] = 0;
    __syncthreads();
    for (int i = tid; i < ncap; i += 1024)
        atomicAdd(&cellcnt[bufA[i].y & 127u], 1);
    __syncthreads();
    if (tid < TCELLS) sc[tid] = (cellcnt[tid] + 7) & ~7;
    __syncthreads();
#pragma unroll
    for (int off = 1; off < TCELLS; off <<= 1) {
        const int t = (tid < TCELLS && tid >= off) ? sc[tid - off] : 0;
        __syncthreads();
        if (tid < TCELLS) sc[tid] += t;
        __syncthreads();
    }
    if (tid < TCELLS) {
        celloff[tid] = sc[tid] - ((cellcnt[tid] + 7) & ~7);
        cellcur[tid] = 0;
    }
    __syncthreads();
    const int padtotal = sc[TCELLS - 1];
    for (int i = tid; i < padtotal; i += 1024) bufB[i] = make_uint2(0u, 0u);
    __syncthreads();
    for (int i = tid; i < ncap; i += 1024) {
        const uint2 e = bufA[i];
        const int c = (int)(e.y & 127u);
        bufB[celloff[c] + atomicAdd(&cellcur[c], 1)] = e;
    }
    __syncthreads();   // bufA dead; sacc live

    for (int c = wv; c < TCELLS; c += 16) {
        const int s0 = celloff[c];
        const int pc = (cellcnt[c] + 7) & ~7;
        float a0 = 0.f, a1 = 0.f;
        for (int i = 0; i < pc; i += 8) {
            uint2 e[8];
#pragma unroll
            for (int r = 0; r < 8; ++r) e[r] = bufB[s0 + i + r];
            if (lane < 40) {
                unsigned u[8];
#pragma unroll
                for (int r = 0; r < 8; ++r)
                    u[r] = *(const unsigned*)(ctx + (e[r].y >> 7) + 2 * lane);
#pragma unroll
                for (int r = 0; r < 8; ++r) {
                    const float d  = __uint_as_float(e[r].x);
                    a0 += d * __uint_as_float(u[r] << 16);
                    a1 += d * __uint_as_float(u[r] & 0xffff0000u);
                }
            }
        }
        if (lane < 40) {
            sacc[2 * lane][c]     = a0;
            sacc[2 * lane + 1][c] = a1;
        }
    }

    // slow path for bucket overflow (correctness only)
    if (total > CAP) {
        for (int sgi = 0; sgi < SEGS; ++sgi) {
            const int dstb = segofs[sgi];
            const int n    = segcnt[sgi];
            if (dstb + n <= CAP) continue;
            const uint2* sp = plist + (size_t)(blk0 + sgi) * EPB
                              + ofsmat[(size_t)(blk0 + sgi) * NTILE + tile];
            const int i0 = (CAP > dstb) ? (CAP - dstb) : 0;
            for (int i = i0; i < n; ++i) {
                const uint2 e = sp[i];
                const int c = (int)(e.y & 127u);
                if ((c & 15) == wv && lane < 40) {
                    const unsigned u = *(const unsigned*)(ctx + (e.y >> 7) + 2 * lane);
                    const float dep = __uint_as_float(e.x);
                    sacc[2 * lane][c]     += dep * __uint_as_float(u << 16);
                    sacc[2 * lane + 1][c] += dep * __uint_as_float(u & 0xffff0000u);
                }
            }
        }
    }
    __syncthreads();

    // epilogue: full 64B line writes to (B,C,H,W)
    const int tl = bucket & 127;
    const int tr = tl >> 3;
    const int tc = tl & 7;
    const int c0  = tid >> 4;
    const int col = tid & 15;
#pragma unroll
    for (int cc = c0; cc < CTX; cc += 64) {
#pragma unroll
        for (int r = 0; r < 8; ++r) {
            out[((size_t)(b * CTX + cc)) * BEVHW + (tr * 8 + r) * 128 + tc * 16 + col]
                = sacc[cc][r * 16 + col];
        }
    }
}

extern "C" void kernel_launch(void* const* d_in, const int* in_sizes, int n_in,
                              void* d_out, int out_size, void* d_ws, size_t ws_size,
                              hipStream_t stream)
{
    const float* img  = (const float*)d_in[0];
    const float* w    = (const float*)d_in[4];
    const float* bias = (const float*)d_in[5];
    const int*   geom = (const int*)d_in[6];
    float*       out  = (float*)d_out;

    float* ws = (float*)d_ws;
    unsigned short* whl = (unsigned short*)ws;
    __hip_bfloat16* ctx = (__hip_bfloat16*)(ws + CTX_OFF);
    int*   cntmat = (int*)(ws + CNTMAT_OFF);
    int*   ofsmat = (int*)(ws + OFSMAT_OFF);
    uint2* plist  = (uint2*)(ws + PLIST_OFF);

    // 0. W -> bf16 hi/lo planes (L2-resident, 147 KB)
    wsplit_kernel<<<O_PAD, 256, 0, stream>>>(w, whl);

    // 1. MFMA GEMM (hi/lo split) + fused bias/softmax/binning epilogue
    {
        dim3 grid(NPXT, BNPAIR);   // 22 x 24 = 528 blocks, 128 threads
        gemm_fused<<<grid, 128, 0, stream>>>(img, whl, bias, geom, ctx,
                                             plist, cntmat, ofsmat);
    }

    // 2. fused cell-sort + gather per bucket, coalesced (B,C,H,W) writes
    gather_kernel<<<NBUCKET, 1024, 0, stream>>>(plist, cntmat, ofsmat,
                                                (const unsigned short*)ctx, out);
}